// Round 8
// baseline (32053.552 us; speedup 1.0000x reference)
//
#include <hip/hip_runtime.h>
#include <hip/hip_cooperative_groups.h>
#include <cmath>

namespace cg = cooperative_groups;

constexpr int kB = 32, kS = 32, kE = 512, kH = 8, kV = 10000, kNB = 4;
constexpr int kQ = 3 * kE;  // 1536
constexpr int ROWS = 8;     // rows per tail chunk

// ---------------- device scratch ----------------
__device__ float g_w[kB * kS];
__device__ float g_pe[kS * kE];
__device__ float g_Y[kB * kS * kE];
__device__ float g_qkvbuf[kNB][kB * kS * kQ];
__device__ float g_actb[kNB][kB * kS * kE];
__device__ float g_logits[kB * kV];
__device__ float g_U[kNB * kE * kH];
__device__ float g_a0[kNB * kH];
__device__ float g_G[kNB * kH * kE];
__device__ float g_c0[kNB * kE];
__device__ unsigned g_bar[kB][32];      // 128B-padded per-group barrier counters
__device__ unsigned g_flag[kB][4][32];  // 128B-padded per-(group,chunk) act-ready epochs

// ---------------- setup kernels (unchanged, verified) ----------------
__global__ void onehot_k(float* __restrict__ out) {
    int i = blockIdx.x * 256 + threadIdx.x;
    if (i >= kB * kV) return;
    int b = i / kV, v = i - b * kV;
    out[(size_t)b * kS * kV + v] = (v == 0) ? 1.f : 0.f;
}

__global__ void pe_k(float* __restrict__ pe) {
    int i = blockIdx.x * 256 + threadIdx.x;  // < kS*kE
    int s = i >> 9, e = i & 511;
    int base = e & ~1;
    float div = expf((float)base * (-logf(10000.f) / (float)kE));
    float ang = (float)s * div;
    pe[i] = (e & 1) ? cosf(ang) : sinf(ang);
}

__global__ void compute_w_k(const float* __restrict__ noise, const float* __restrict__ W_in,
                            const float* __restrict__ b_in, float* __restrict__ w) {
    __shared__ float X[kB * kS], T[kB * kS];
    int tid = threadIdx.x;  // 1024
    X[tid] = noise[tid];
    __syncthreads();
    int r = tid >> 5, c = tid & 31;
    float acc = b_in[c];
    for (int k = 0; k < 32; ++k) acc = fmaf(X[r * 32 + k], W_in[k * 32 + c], acc);
    T[tid] = acc;
    __syncthreads();
    acc = b_in[32 + c];
    for (int k = 0; k < 32; ++k) acc = fmaf(T[r * 32 + k], W_in[1024 + k * 32 + c], acc);
    w[tid] = acc;
}

__global__ __launch_bounds__(256) void initY_k(const float* __restrict__ emb,
                                               const float* __restrict__ pe,
                                               float* __restrict__ Y,
                                               const float* __restrict__ Wq0,
                                               const float* __restrict__ bq0,
                                               float* __restrict__ qkv0) {
    __shared__ float ys[kE];
    int b = blockIdx.x, tid = threadIdx.x;
    for (int j = tid; j < kE; j += 256) {
        float v = emb[j] + pe[j];
        Y[(size_t)(b * kS) * kE + j] = v;
        ys[j] = v;
    }
    __syncthreads();
#pragma unroll
    for (int m = 0; m < 6; ++m) {
        int j = tid + 256 * m;
        const float* Wc = Wq0 + (size_t)(j >> 9) * (kE * kE) + (j & 511);
        float acc = bq0[j];
        for (int k = 0; k < kE; ++k) acc = fmaf(ys[k], Wc[(size_t)k * kE], acc);
        qkv0[(size_t)(b * kS) * kQ + j] = acc;
    }
}

__global__ __launch_bounds__(256) void precross_k(const float* __restrict__ Wca,
                                                  const float* __restrict__ bca,
                                                  float* __restrict__ U, float* __restrict__ a0,
                                                  float* __restrict__ G, float* __restrict__ c0) {
    int n = blockIdx.x;
    const float* Wq = Wca + (size_t)n * 4 * kE * kE;
    const float* Wk = Wq + kE * kE;
    const float* Wv = Wk + kE * kE;
    const float* Wo = Wv + kE * kE;
    const float* bq = bca + n * 4 * kE;
    const float* bv = bq + 2 * kE;
    const float* bo = bq + 3 * kE;
    __shared__ float ck[kE], cv[kE];
    int tid = threadIdx.x;
    for (int j = tid; j < kE; j += 256) {
        float s1 = 0.f, s2 = 0.f;
        for (int e = 0; e < kE; ++e) { s1 += Wk[e * kE + j]; s2 += Wv[e * kE + j]; }
        ck[j] = s1; cv[j] = s2;
    }
    __syncthreads();
    for (int p = tid; p < kE * kH; p += 256) {
        int e = p >> 3, h = p & 7;
        float acc = 0.f;
        for (int d = 0; d < 64; ++d) acc = fmaf(Wq[e * kE + h * 64 + d], ck[h * 64 + d], acc);
        U[n * kE * kH + p] = acc;
    }
    if (tid < kH) {
        float acc = 0.f;
        for (int d = 0; d < 64; ++d) acc = fmaf(bq[tid * 64 + d], ck[tid * 64 + d], acc);
        a0[n * kH + tid] = acc;
    }
    for (int p = tid; p < kH * kE; p += 256) {
        int h = p >> 9, j = p & 511;
        float acc = 0.f;
        for (int d = 0; d < 64; ++d) acc = fmaf(cv[h * 64 + d], Wo[(h * 64 + d) * kE + j], acc);
        G[n * kH * kE + p] = acc;
    }
    for (int j = tid; j < kE; j += 256) {
        float acc = bo[j];
        for (int e = 0; e < kE; ++e) acc = fmaf(bv[e], Wo[e * kE + j], acc);
        c0[n * kE + j] = acc;
    }
}

// ---------------- 512-thread (8-wave) helpers (verified math order) ----------------
__device__ __forceinline__ void rowsum8_512(float v[ROWS], float (*red)[ROWS], float out[ROWS]) {
    int lane = threadIdx.x & 63, w = threadIdx.x >> 6;
#pragma unroll
    for (int i = 0; i < ROWS; ++i) {
        float s = v[i];
#pragma unroll
        for (int o = 32; o > 0; o >>= 1) s += __shfl_xor(s, o);
        v[i] = s;
    }
    if (lane == 0) {
#pragma unroll
        for (int i = 0; i < ROWS; ++i) red[w][i] = v[i];
    }
    __syncthreads();
#pragma unroll
    for (int i = 0; i < ROWS; ++i) {
        float s = 0.f;
#pragma unroll
        for (int w2 = 0; w2 < 8; ++w2) s += red[w2][i];
        out[i] = s;
    }
    __syncthreads();
}

__device__ __forceinline__ void ln8_512(float val[ROWS], const float* __restrict__ g,
                                        const float* __restrict__ bb, float (*red)[ROWS], int j) {
    float s[ROWS], mean[ROWS], var[ROWS];
#pragma unroll
    for (int i = 0; i < ROWS; ++i) s[i] = val[i];
    rowsum8_512(s, red, mean);
#pragma unroll
    for (int i = 0; i < ROWS; ++i) {
        mean[i] *= (1.f / (float)kE);
        val[i] -= mean[i];
        s[i] = val[i] * val[i];
    }
    rowsum8_512(s, red, var);
    float gj = g[j], bj = bb[j];
#pragma unroll
    for (int i = 0; i < ROWS; ++i) {
        float rstd = rsqrtf(var[i] * (1.f / (float)kE) + 1e-5f);
        val[i] = gj * val[i] * rstd + bj;
    }
}

// GEMM phase: out[i][j] = sum_k in[i][k]*W[k][j]; 4-way k-split + ordered LDS reduce.
__device__ __forceinline__ void gemm_phase(const float (*in)[kE], const float* __restrict__ W,
                                           float (*out)[kE], int kg, int jt) {
    float acc[ROWS][4];
#pragma unroll
    for (int i = 0; i < ROWS; ++i)
#pragma unroll
        for (int c = 0; c < 4; ++c) acc[i][c] = 0.f;
    const int kbase = kg * 128;
    const int j4 = jt * 4;
#pragma unroll 4
    for (int kk = 0; kk < 128; kk += 4) {
        const float4 wv0 = *(const float4*)(W + (size_t)(kbase + kk + 0) * kE + j4);
        const float4 wv1 = *(const float4*)(W + (size_t)(kbase + kk + 1) * kE + j4);
        const float4 wv2 = *(const float4*)(W + (size_t)(kbase + kk + 2) * kE + j4);
        const float4 wv3 = *(const float4*)(W + (size_t)(kbase + kk + 3) * kE + j4);
#pragma unroll
        for (int i = 0; i < ROWS; ++i) {
            const float4 av = *(const float4*)(&in[i][kbase + kk]);
            acc[i][0] = fmaf(av.x, wv0.x, acc[i][0]);
            acc[i][0] = fmaf(av.y, wv1.x, acc[i][0]);
            acc[i][0] = fmaf(av.z, wv2.x, acc[i][0]);
            acc[i][0] = fmaf(av.w, wv3.x, acc[i][0]);
            acc[i][1] = fmaf(av.x, wv0.y, acc[i][1]);
            acc[i][1] = fmaf(av.y, wv1.y, acc[i][1]);
            acc[i][1] = fmaf(av.z, wv2.y, acc[i][1]);
            acc[i][1] = fmaf(av.w, wv3.y, acc[i][1]);
            acc[i][2] = fmaf(av.x, wv0.z, acc[i][2]);
            acc[i][2] = fmaf(av.y, wv1.z, acc[i][2]);
            acc[i][2] = fmaf(av.z, wv2.z, acc[i][2]);
            acc[i][2] = fmaf(av.w, wv3.z, acc[i][2]);
            acc[i][3] = fmaf(av.x, wv0.w, acc[i][3]);
            acc[i][3] = fmaf(av.y, wv1.w, acc[i][3]);
            acc[i][3] = fmaf(av.z, wv2.w, acc[i][3]);
            acc[i][3] = fmaf(av.w, wv3.w, acc[i][3]);
        }
    }
    if (kg == 0) {
#pragma unroll
        for (int i = 0; i < ROWS; ++i)
            *(float4*)(&out[i][j4]) = make_float4(acc[i][0], acc[i][1], acc[i][2], acc[i][3]);
    }
    __syncthreads();
#pragma unroll
    for (int r = 1; r < 4; ++r) {
        if (kg == r) {
#pragma unroll
            for (int i = 0; i < ROWS; ++i) {
                float4 c = *(float4*)(&out[i][j4]);
                c.x += acc[i][0]; c.y += acc[i][1]; c.z += acc[i][2]; c.w += acc[i][3];
                *(float4*)(&out[i][j4]) = c;
            }
        }
        __syncthreads();
    }
}

// ---------------- persistent cooperative kernel: async batch-groups + flag pipeline ----------------
__global__ __launch_bounds__(512, 4) void genloop_k(
    const float* w_, const float* pe_, float* Y_, float* qkvb_, float* actb_, float* lg_,
    const float* U_, const float* a0_, const float* G_, const float* c0_, float* out,
    const float* emb, const float* Wsa, const float* bsa, const float* Wff,
    const float* bff, const float* ln_g, const float* ln_b, const float* softW,
    const float* softb, int gbv, int gbShift) {
    cg::grid_group grid = cg::this_grid();
    __shared__ __align__(16) float smem[16384];
    float (*bufA)[kE] = (float (*)[kE])smem;                   // 8x512
    float (*bufC)[kE] = (float (*)[kE])(smem + ROWS * kE);     // 8x512
    float* Us = smem + 2 * ROWS * kE;                          // 4096
    float* aux = smem + 2 * ROWS * kE + kE * kH;               // base 12288
    float (*att_s)[kS] = (float (*)[kS])aux;                   // 8x32
    float (*alp)[kH][4] = (float (*)[kH][4])(aux + 256);       // 8x8x4
    float (*om_s)[kH] = (float (*)[kH])(aux + 512);            // 64
    float* w_s = aux + 576;                                    // 32
    float (*red)[ROWS] = (float (*)[ROWS])(aux + 608);         // 64

    const int blk = blockIdx.x;
    const int b = blk >> gbShift;
    const int gb = blk & (gbv - 1);
    const int tid = threadIdx.x;
    const int lane = tid & 63, wid = tid >> 6;
    const int kg = tid >> 7, jt = tid & 127;

    // reset this group's barrier + flags (replay safety), then one global rendezvous
    if (gb == 0 && tid == 0) {
        g_bar[b][0] = 0u;
        g_flag[b][0][0] = 0u; g_flag[b][1][0] = 0u; g_flag[b][2][0] = 0u; g_flag[b][3][0] = 0u;
    }
    grid.sync();
    unsigned phase = 0;

    auto gbar = [&]() {
        __syncthreads();
        ++phase;
        if (tid == 0) {
            __threadfence();
            atomicAdd(&g_bar[b][0], 1u);
            const unsigned target = phase * (unsigned)gbv;
            while (__hip_atomic_load(&g_bar[b][0], __ATOMIC_ACQUIRE,
                                     __HIP_MEMORY_SCOPE_AGENT) < target)
                __builtin_amdgcn_s_sleep(2);
            __threadfence();
        }
        __syncthreads();
    };

    for (int tok = 1; tok < kS; ++tok) {
        const int t = tok;
        const int nch = (t + ROWS - 1) >> 3;

        for (int n = 0; n < kNB; ++n) {
            const float* qkv_cur = qkvb_ + (size_t)n * (kB * kS * kQ);
            const float* in_res = (n == 0) ? Y_ : (actb_ + (size_t)(n - 1) * (kB * kS * kE));
            float* act_out = actb_ + (size_t)n * (kB * kS * kE);
            const float* Wn = Wsa + (size_t)n * 4 * kE * kE;
            const float* bn = bsa + (size_t)n * 4 * kE;
            const float* Wo = Wn + 3 * kE * kE;
            const float* bo = bn + 3 * kE;
            const float* Wf1 = Wff + (size_t)n * 2 * kE * kE;
            const float* fb1 = bff + (size_t)n * 2 * kE;
            const float* Wf2 = Wf1 + kE * kE;
            const float* fb2 = fb1 + kE;
            const float* g0 = ln_g + (size_t)(n * 3 + 0) * kE, *lb0 = ln_b + (size_t)(n * 3 + 0) * kE;
            const float* g1 = ln_g + (size_t)(n * 3 + 1) * kE, *lb1 = ln_b + (size_t)(n * 3 + 1) * kE;
            const float* g2 = ln_g + (size_t)(n * 3 + 2) * kE, *lb2 = ln_b + (size_t)(n * 3 + 2) * kE;
            const float* Um = U_ + n * kE * kH;
            const float* a0m = a0_ + n * kH;
            const float* Gm = G_ + n * kH * kE;
            const float* c0m = c0_ + n * kE;
            const unsigned epoch = (unsigned)((tok - 1) * 3 + n + 1);  // for n<3 flags

            const bool tail_active = (n == 3) ? (gb == 0) : (gb < nch);
            const int c = (n == 3) ? ((t - 1) >> 3) : gb;

            if (tail_active) {
                const int r0 = c * ROWS;
                int rr[ROWS]; bool valid[ROWS];
#pragma unroll
                for (int i = 0; i < ROWS; ++i) {
                    int r = r0 + i;
                    valid[i] = (r < t);
                    rr[i] = valid[i] ? r : (t - 1);
                }
                for (int p = tid; p < ROWS * kE; p += 512) {
                    int i = p >> 9, d = p & 511;
                    bufA[i][d] = qkv_cur[(size_t)(b * kS + rr[i]) * kQ + d];
                }
                for (int p = tid; p < kE * kH; p += 512) Us[p] = Um[p];
                if (tid < t) w_s[tid] = w_[b * kS + tid];
                __syncthreads();

                // self-attention: wave wid owns row wid
                {
                    const int i = wid;
                    for (int h = 0; h < kH; ++h) {
                        float sc = -3.0e38f;
                        if (lane < t) {
                            const float* Kr = qkv_cur + (size_t)(b * kS + lane) * kQ + kE + h * 64;
                            float a = 0.f;
#pragma unroll
                            for (int d4 = 0; d4 < 16; ++d4) {
                                const float4 kv = *(const float4*)(Kr + d4 * 4);
                                const float4 qv = *(const float4*)(&bufA[i][h * 64 + d4 * 4]);
                                a = fmaf(qv.x, kv.x, a); a = fmaf(qv.y, kv.y, a);
                                a = fmaf(qv.z, kv.z, a); a = fmaf(qv.w, kv.w, a);
                            }
                            sc = a * 0.125f;
                        }
                        float m = sc;
#pragma unroll
                        for (int o = 32; o > 0; o >>= 1) m = fmaxf(m, __shfl_xor(m, o));
                        float e = (lane < t) ? expf(sc - m) : 0.f;
                        float ss = e;
#pragma unroll
                        for (int o = 32; o > 0; o >>= 1) ss += __shfl_xor(ss, o);
                        if (lane < t) att_s[wid][lane] = e / ss;
                        float acc = 0.f;
                        const float* Vb = qkv_cur + (size_t)(b * kS) * kQ + 2 * kE + h * 64 + lane;
                        for (int k = 0; k < t; ++k) acc = fmaf(att_s[wid][k], Vb[(size_t)k * kQ], acc);
                        bufA[i][h * 64 + lane] = acc;
                    }
                }
                __syncthreads();

                float val[ROWS], hreg[ROWS], h2reg[ROWS];

                // proj + residual + LN -> h
                gemm_phase(bufA, Wo, bufC, kg, jt);
                {
                    float btid = bo[tid];
#pragma unroll
                    for (int i = 0; i < ROWS; ++i)
                        val[i] = bufC[i][tid] + btid + in_res[(size_t)(b * kS + rr[i]) * kE + tid];
                    ln8_512(val, g0, lb0, red, tid);
#pragma unroll
                    for (int i = 0; i < ROWS; ++i) { hreg[i] = val[i]; bufA[i][tid] = val[i]; }
                }
                __syncthreads();

                // reduced cross-attn
                if (tid < 256) {
                    int i = tid >> 5, h = (tid >> 2) & 7, cs = tid & 3;
                    float a = 0.f;
                    for (int e = cs * 128; e < cs * 128 + 128; ++e)
                        a = fmaf(bufA[i][e], Us[e * kH + h], a);
                    alp[i][h][cs] = a;
                }
                __syncthreads();
                if (tid < 64) {
                    int i = tid >> 3, h = tid & 7;
                    float a = a0m[h] + alp[i][h][0] + alp[i][h][1] + alp[i][h][2] + alp[i][h][3];
                    a *= 0.125f;
                    float mm = -3.0e38f;
                    for (int s = 0; s < t; ++s) mm = fmaxf(mm, a * w_s[s]);
                    float se = 0.f, sw = 0.f;
                    for (int s = 0; s < t; ++s) {
                        float ex = expf(a * w_s[s] - mm);
                        se += ex;
                        sw = fmaf(ex, w_s[s], sw);
                    }
                    om_s[i][h] = sw / se;
                }
                __syncthreads();

                // crossout + residual(h) + LN -> h2
                {
                    float ctid = c0m[tid];
#pragma unroll
                    for (int i = 0; i < ROWS; ++i) {
                        float v = ctid + hreg[i];
#pragma unroll
                        for (int h = 0; h < kH; ++h) v = fmaf(om_s[i][h], Gm[h * kE + tid], v);
                        val[i] = v;
                    }
                    ln8_512(val, g1, lb1, red, tid);
#pragma unroll
                    for (int i = 0; i < ROWS; ++i) { h2reg[i] = val[i]; bufA[i][tid] = val[i]; }
                }
                __syncthreads();

                // FF1 + relu
                gemm_phase(bufA, Wf1, bufC, kg, jt);
                {
                    float btid = fb1[tid];
#pragma unroll
                    for (int i = 0; i < ROWS; ++i) val[i] = fmaxf(bufC[i][tid] + btid, 0.f);
#pragma unroll
                    for (int i = 0; i < ROWS; ++i) bufA[i][tid] = val[i];
                }
                __syncthreads();

                // FF2 + residual(h2) + LN -> act_out, then publish chunk flag
                gemm_phase(bufA, Wf2, bufC, kg, jt);
                {
                    float btid = fb2[tid];
#pragma unroll
                    for (int i = 0; i < ROWS; ++i) val[i] = bufC[i][tid] + btid + h2reg[i];
                    ln8_512(val, g2, lb2, red, tid);
#pragma unroll
                    for (int i = 0; i < ROWS; ++i)
                        if (valid[i]) act_out[(size_t)(b * kS + r0 + i) * kE + tid] = val[i];
                }
                if (n < 3) {
                    __syncthreads();
                    if (tid == 0) {
                        __threadfence();
                        __hip_atomic_store(&g_flag[b][c][0], epoch, __ATOMIC_RELEASE,
                                           __HIP_MEMORY_SCOPE_AGENT);
                    }
                }
            } else if (n < 3 && gb >= 4) {
                // ---- pipelined QKV for decoder block n+1 ----
                const float* Wqn = Wsa + (size_t)(n + 1) * 4 * kE * kE;
                const float* bqn = bsa + (size_t)(n + 1) * 4 * kE;
                float* qnext = qkvb_ + (size_t)(n + 1) * (kB * kS * kQ);
                for (int tk = gb - 4; tk < 3 * nch; tk += gbv - 4) {
                    const int slab = tk / nch;
                    const int cch = tk - slab * nch;
                    if (tid == 0) {
                        while (__hip_atomic_load(&g_flag[b][cch][0], __ATOMIC_ACQUIRE,
                                                 __HIP_MEMORY_SCOPE_AGENT) < epoch)
                            __builtin_amdgcn_s_sleep(2);
                        __threadfence();
                    }
                    __syncthreads();
                    const int r0 = cch * ROWS;
                    int rr[ROWS]; bool valid[ROWS];
#pragma unroll
                    for (int i = 0; i < ROWS; ++i) {
                        int r = r0 + i;
                        valid[i] = (r < t);
                        rr[i] = valid[i] ? r : (t - 1);
                    }
                    for (int p = tid; p < ROWS * kE; p += 512) {
                        int i = p >> 9, d = p & 511;
                        bufA[i][d] = act_out[(size_t)(b * kS + rr[i]) * kE + d];
                    }
                    __syncthreads();
                    gemm_phase(bufA, Wqn + (size_t)slab * kE * kE, bufC, kg, jt);
                    float bj = bqn[slab * kE + tid];
#pragma unroll
                    for (int i = 0; i < ROWS; ++i)
                        if (valid[i])
                            qnext[(size_t)(b * kS + r0 + i) * kQ + slab * kE + tid] =
                                bufC[i][tid] + bj;
                    __syncthreads();
                }
            }
            gbar();
        }

        // ---- logits: gbv blocks x (kV/gbv) cols ----
        {
            const int cols = kV / gbv;  // 625 (gbv=16) or 1250 (gbv=8)
            float* xs = smem;
            const float* ab3 = actb_ + (size_t)3 * (kB * kS * kE);
            xs[tid] = ab3[(size_t)(b * kS + (t - 1)) * kE + tid];
            __syncthreads();
            const int jend = (gb + 1) * cols;
            for (int j = gb * cols + tid; j < jend; j += 512) {
                float acc = softb[j];
#pragma unroll 8
                for (int k = 0; k < kE; ++k) acc = fmaf(xs[k], softW[(size_t)k * kV + j], acc);
                lg_[(size_t)b * kV + j] = acc;
            }
        }
        gbar();

        // ---- softmax + argmax + probs + Y row + qkv0 row (block 0 of group) ----
        if (gb == 0) {
            float* redf = smem;
            int* redi = (int*)(smem + 16);
            float* ys = smem + 64;
            const float* lg = lg_ + (size_t)b * kV;
            float m = -3.4e38f;
            int mi = 0;
            for (int j = tid; j < kV; j += 512) {
                float v = lg[j];
                if (v > m) { m = v; mi = j; }
            }
#pragma unroll
            for (int o = 32; o > 0; o >>= 1) {
                float m2 = __shfl_xor(m, o);
                int i2 = __shfl_xor(mi, o);
                if (m2 > m || (m2 == m && i2 < mi)) { m = m2; mi = i2; }
            }
            if (lane == 0) { redf[wid] = m; redi[wid] = mi; }
            __syncthreads();
            m = redf[0]; mi = redi[0];
#pragma unroll
            for (int w2 = 1; w2 < 8; ++w2)
                if (redf[w2] > m || (redf[w2] == m && redi[w2] < mi)) { m = redf[w2]; mi = redi[w2]; }
            __syncthreads();
            float ssum = 0.f;
            for (int j = tid; j < kV; j += 512) ssum += expf(lg[j] - m);
#pragma unroll
            for (int o = 32; o > 0; o >>= 1) ssum += __shfl_xor(ssum, o);
            if (lane == 0) redf[wid] = ssum;
            __syncthreads();
            ssum = 0.f;
#pragma unroll
            for (int w2 = 0; w2 < 8; ++w2) ssum += redf[w2];
            float inv = 1.f / ssum;
            float* orow = out + ((size_t)b * kS + tok) * kV;
            for (int j = tid; j < kV; j += 512) orow[j] = expf(lg[j] - m) * inv;
            const float* erow = emb + (size_t)mi * kE;
            const float* pet = pe_ + (size_t)tok * kE;
            float* yrow = Y_ + (size_t)(b * kS + tok) * kE;
            for (int j = tid; j < kE; j += 512) {
                float v = erow[j] + pet[j];
                yrow[j] = v;
                ys[j] = v;
            }
            __syncthreads();
            // fused qkv0 row for the new token (3 slabs, same chain order as initY_k)
#pragma unroll
            for (int mq = 0; mq < 3; ++mq) {
                int j = mq * 512 + tid;
                const float* Wc = Wsa + (size_t)(j >> 9) * (kE * kE) + (j & 511);
                float acc = bsa[j];
#pragma unroll 8
                for (int k = 0; k < kE; ++k) acc = fmaf(ys[k], Wc[(size_t)k * kE], acc);
                qkvb_[(size_t)(b * kS + tok) * kQ + j] = acc;
            }
        }
        gbar();
    }
}

// ---------------- host ----------------
extern "C" void kernel_launch(void* const* d_in, const int* in_sizes, int n_in, void* d_out,
                              int out_size, void* d_ws, size_t ws_size, hipStream_t stream) {
    const float* noise = (const float*)d_in[0];
    const float* W_in = (const float*)d_in[1];
    const float* b_in = (const float*)d_in[2];
    const float* emb = (const float*)d_in[3];
    const float* Wsa = (const float*)d_in[4];
    const float* bsa = (const float*)d_in[5];
    const float* Wca = (const float*)d_in[6];
    const float* bca = (const float*)d_in[7];
    const float* Wff = (const float*)d_in[8];
    const float* bff = (const float*)d_in[9];
    const float* ln_g = (const float*)d_in[10];
    const float* ln_b = (const float*)d_in[11];
    const float* softW = (const float*)d_in[12];
    const float* softb = (const float*)d_in[13];
    float* out = (float*)d_out;
    (void)d_ws; (void)ws_size; (void)in_sizes; (void)n_in; (void)out_size;

    float *w_, *pe_, *Y_, *qkvb_, *actb_, *lg_, *U_, *a0_, *G_, *c0_;
    hipGetSymbolAddress((void**)&w_, HIP_SYMBOL(g_w));
    hipGetSymbolAddress((void**)&pe_, HIP_SYMBOL(g_pe));
    hipGetSymbolAddress((void**)&Y_, HIP_SYMBOL(g_Y));
    hipGetSymbolAddress((void**)&qkvb_, HIP_SYMBOL(g_qkvbuf));
    hipGetSymbolAddress((void**)&actb_, HIP_SYMBOL(g_actb));
    hipGetSymbolAddress((void**)&lg_, HIP_SYMBOL(g_logits));
    hipGetSymbolAddress((void**)&U_, HIP_SYMBOL(g_U));
    hipGetSymbolAddress((void**)&a0_, HIP_SYMBOL(g_a0));
    hipGetSymbolAddress((void**)&G_, HIP_SYMBOL(g_G));
    hipGetSymbolAddress((void**)&c0_, HIP_SYMBOL(g_c0));

    dim3 blk(256);
    hipLaunchKernelGGL(onehot_k, dim3((kB * kV + 255) / 256), blk, 0, stream, out);
    hipLaunchKernelGGL(pe_k, dim3(kS * kE / 256), blk, 0, stream, pe_);
    hipLaunchKernelGGL(compute_w_k, dim3(1), dim3(1024), 0, stream, noise, W_in, b_in, w_);
    hipLaunchKernelGGL(initY_k, dim3(kB), blk, 0, stream, emb, pe_, Y_, Wsa, bsa, qkvb_);
    hipLaunchKernelGGL(precross_k, dim3(kNB), blk, 0, stream, Wca, bca, U_, a0_, G_, c0_);

    // pick group size from achievable co-residency (deterministic per device)
    int maxb = 1;
    hipOccupancyMaxActiveBlocksPerMultiprocessor(&maxb, genloop_k, 512, 0);
    int gbv = (maxb >= 2) ? 16 : 8;
    int gbShift = (maxb >= 2) ? 4 : 3;
    int nblk = kB * gbv;

    void* kargs[] = {&w_, &pe_, &Y_, &qkvb_, &actb_, &lg_, &U_, &a0_, &G_, &c0_,
                     &out, &emb, &Wsa, &bsa, &Wff, &bff, &ln_g, &ln_b, &softW, &softb,
                     &gbv, &gbShift};
    hipLaunchCooperativeKernel((const void*)genloop_k, dim3(nblk), dim3(512), kargs, 0, stream);
}

// Round 9
// 22726.411 us; speedup vs baseline: 1.4104x; 1.4104x over previous
//
#include <hip/hip_runtime.h>
#include <cmath>

constexpr int kB = 32, kS = 32, kE = 512, kH = 8, kV = 10000, kNB = 4;
constexpr int kQ = 3 * kE;  // 1536
constexpr int ROWS = 8;     // rows per tail chunk

// ---------------- device scratch ----------------
__device__ float g_w[kB * kS];
__device__ float g_pe[kS * kE];
__device__ float g_Y[kB * kS * kE];
__device__ float g_qkvbuf[kNB][kB * kS * kQ];
__device__ float g_actb[kNB][kB * kS * kE];
__device__ float g_logits[kB * kV];
__device__ float g_U[kNB * kE * kH];
__device__ float g_a0[kNB * kH];
__device__ float g_G[kNB * kH * kE];
__device__ float g_c0[kNB * kE];

// ---------------- setup kernels (unchanged, verified) ----------------
__global__ void onehot_k(float* __restrict__ out) {
    int i = blockIdx.x * 256 + threadIdx.x;
    if (i >= kB * kV) return;
    int b = i / kV, v = i - b * kV;
    out[(size_t)b * kS * kV + v] = (v == 0) ? 1.f : 0.f;
}

__global__ void pe_k(float* __restrict__ pe) {
    int i = blockIdx.x * 256 + threadIdx.x;  // < kS*kE
    int s = i >> 9, e = i & 511;
    int base = e & ~1;
    float div = expf((float)base * (-logf(10000.f) / (float)kE));
    float ang = (float)s * div;
    pe[i] = (e & 1) ? cosf(ang) : sinf(ang);
}

__global__ void compute_w_k(const float* __restrict__ noise, const float* __restrict__ W_in,
                            const float* __restrict__ b_in, float* __restrict__ w) {
    __shared__ float X[kB * kS], T[kB * kS];
    int tid = threadIdx.x;  // 1024
    X[tid] = noise[tid];
    __syncthreads();
    int r = tid >> 5, c = tid & 31;
    float acc = b_in[c];
    for (int k = 0; k < 32; ++k) acc = fmaf(X[r * 32 + k], W_in[k * 32 + c], acc);
    T[tid] = acc;
    __syncthreads();
    acc = b_in[32 + c];
    for (int k = 0; k < 32; ++k) acc = fmaf(T[r * 32 + k], W_in[1024 + k * 32 + c], acc);
    w[tid] = acc;
}

__global__ __launch_bounds__(256) void initY_k(const float* __restrict__ emb,
                                               const float* __restrict__ pe,
                                               float* __restrict__ Y,
                                               const float* __restrict__ Wq0,
                                               const float* __restrict__ bq0,
                                               float* __restrict__ qkv0) {
    __shared__ float ys[kE];
    int b = blockIdx.x, tid = threadIdx.x;
    for (int j = tid; j < kE; j += 256) {
        float v = emb[j] + pe[j];
        Y[(size_t)(b * kS) * kE + j] = v;
        ys[j] = v;
    }
    __syncthreads();
#pragma unroll
    for (int m = 0; m < 6; ++m) {
        int j = tid + 256 * m;
        const float* Wc = Wq0 + (size_t)(j >> 9) * (kE * kE) + (j & 511);
        float acc = bq0[j];
        for (int k = 0; k < kE; ++k) acc = fmaf(ys[k], Wc[(size_t)k * kE], acc);
        qkv0[(size_t)(b * kS) * kQ + j] = acc;
    }
}

__global__ __launch_bounds__(256) void precross_k(const float* __restrict__ Wca,
                                                  const float* __restrict__ bca,
                                                  float* __restrict__ U, float* __restrict__ a0,
                                                  float* __restrict__ G, float* __restrict__ c0) {
    int n = blockIdx.x;
    const float* Wq = Wca + (size_t)n * 4 * kE * kE;
    const float* Wk = Wq + kE * kE;
    const float* Wv = Wk + kE * kE;
    const float* Wo = Wv + kE * kE;
    const float* bq = bca + n * 4 * kE;
    const float* bv = bq + 2 * kE;
    const float* bo = bq + 3 * kE;
    __shared__ float ck[kE], cv[kE];
    int tid = threadIdx.x;
    for (int j = tid; j < kE; j += 256) {
        float s1 = 0.f, s2 = 0.f;
        for (int e = 0; e < kE; ++e) { s1 += Wk[e * kE + j]; s2 += Wv[e * kE + j]; }
        ck[j] = s1; cv[j] = s2;
    }
    __syncthreads();
    for (int p = tid; p < kE * kH; p += 256) {
        int e = p >> 3, h = p & 7;
        float acc = 0.f;
        for (int d = 0; d < 64; ++d) acc = fmaf(Wq[e * kE + h * 64 + d], ck[h * 64 + d], acc);
        U[n * kE * kH + p] = acc;
    }
    if (tid < kH) {
        float acc = 0.f;
        for (int d = 0; d < 64; ++d) acc = fmaf(bq[tid * 64 + d], ck[tid * 64 + d], acc);
        a0[n * kH + tid] = acc;
    }
    for (int p = tid; p < kH * kE; p += 256) {
        int h = p >> 9, j = p & 511;
        float acc = 0.f;
        for (int d = 0; d < 64; ++d) acc = fmaf(cv[h * 64 + d], Wo[(h * 64 + d) * kE + j], acc);
        G[n * kH * kE + p] = acc;
    }
    for (int j = tid; j < kE; j += 256) {
        float acc = bo[j];
        for (int e = 0; e < kE; ++e) acc = fmaf(bv[e], Wo[e * kE + j], acc);
        c0[n * kE + j] = acc;
    }
}

// ---------------- 512-thread (8-wave) helpers (verified math order) ----------------
__device__ __forceinline__ void rowsum8_512(float v[ROWS], float (*red)[ROWS], float out[ROWS]) {
    int lane = threadIdx.x & 63, w = threadIdx.x >> 6;
#pragma unroll
    for (int i = 0; i < ROWS; ++i) {
        float s = v[i];
#pragma unroll
        for (int o = 32; o > 0; o >>= 1) s += __shfl_xor(s, o);
        v[i] = s;
    }
    if (lane == 0) {
#pragma unroll
        for (int i = 0; i < ROWS; ++i) red[w][i] = v[i];
    }
    __syncthreads();
#pragma unroll
    for (int i = 0; i < ROWS; ++i) {
        float s = 0.f;
#pragma unroll
        for (int w2 = 0; w2 < 8; ++w2) s += red[w2][i];
        out[i] = s;
    }
    __syncthreads();
}

__device__ __forceinline__ void ln8_512(float val[ROWS], const float* __restrict__ g,
                                        const float* __restrict__ bb, float (*red)[ROWS], int j) {
    float s[ROWS], mean[ROWS], var[ROWS];
#pragma unroll
    for (int i = 0; i < ROWS; ++i) s[i] = val[i];
    rowsum8_512(s, red, mean);
#pragma unroll
    for (int i = 0; i < ROWS; ++i) {
        mean[i] *= (1.f / (float)kE);
        val[i] -= mean[i];
        s[i] = val[i] * val[i];
    }
    rowsum8_512(s, red, var);
    float gj = g[j], bj = bb[j];
#pragma unroll
    for (int i = 0; i < ROWS; ++i) {
        float rstd = rsqrtf(var[i] * (1.f / (float)kE) + 1e-5f);
        val[i] = gj * val[i] * rstd + bj;
    }
}

// GEMM phase v2: out[i][j] = sum_k in[i][k]*W[k][j].
// 512 threads = 8 k-groups (kg = tid>>6, 64-k slice) x 64 col-threads (jt = tid&63, 8 cols).
// 32 fma per LDS b128 read (vs 16 in v1) -> VALU-bound, not LDS-bound.
__device__ __forceinline__ void gemm_phase8(const float (*in)[kE], const float* __restrict__ W,
                                            float (*out)[kE], int kg, int jt) {
    float acc[ROWS][8];
#pragma unroll
    for (int i = 0; i < ROWS; ++i)
#pragma unroll
        for (int c = 0; c < 8; ++c) acc[i][c] = 0.f;
    const int kbase = kg * 64;
    const int j8 = jt * 8;
#pragma unroll 4
    for (int kk = 0; kk < 64; kk += 4) {
        float4 av[ROWS];
#pragma unroll
        for (int i = 0; i < ROWS; ++i) av[i] = *(const float4*)(&in[i][kbase + kk]);
#pragma unroll
        for (int dk = 0; dk < 4; ++dk) {
            const float* Wr = W + (size_t)(kbase + kk + dk) * kE + j8;
            const float4 wa = *(const float4*)(Wr);
            const float4 wb = *(const float4*)(Wr + 4);
#pragma unroll
            for (int i = 0; i < ROWS; ++i) {
                const float a = (dk == 0) ? av[i].x
                              : (dk == 1) ? av[i].y
                              : (dk == 2) ? av[i].z
                                          : av[i].w;
                acc[i][0] = fmaf(a, wa.x, acc[i][0]);
                acc[i][1] = fmaf(a, wa.y, acc[i][1]);
                acc[i][2] = fmaf(a, wa.z, acc[i][2]);
                acc[i][3] = fmaf(a, wa.w, acc[i][3]);
                acc[i][4] = fmaf(a, wb.x, acc[i][4]);
                acc[i][5] = fmaf(a, wb.y, acc[i][5]);
                acc[i][6] = fmaf(a, wb.z, acc[i][6]);
                acc[i][7] = fmaf(a, wb.w, acc[i][7]);
            }
        }
    }
    // deterministic sequential k-group reduce
    if (kg == 0) {
#pragma unroll
        for (int i = 0; i < ROWS; ++i) {
            *(float4*)(&out[i][j8]) = make_float4(acc[i][0], acc[i][1], acc[i][2], acc[i][3]);
            *(float4*)(&out[i][j8 + 4]) = make_float4(acc[i][4], acc[i][5], acc[i][6], acc[i][7]);
        }
    }
    __syncthreads();
#pragma unroll
    for (int r = 1; r < 8; ++r) {
        if (kg == r) {
#pragma unroll
            for (int i = 0; i < ROWS; ++i) {
                float4 c0 = *(float4*)(&out[i][j8]);
                float4 c1 = *(float4*)(&out[i][j8 + 4]);
                c0.x += acc[i][0]; c0.y += acc[i][1]; c0.z += acc[i][2]; c0.w += acc[i][3];
                c1.x += acc[i][4]; c1.y += acc[i][5]; c1.z += acc[i][6]; c1.w += acc[i][7];
                *(float4*)(&out[i][j8]) = c0;
                *(float4*)(&out[i][j8 + 4]) = c1;
            }
        }
        __syncthreads();
    }
}

// ---------------- fused tail: attn+proj+LN+cross+crossLN+FF1+FF2+LN (+QKV next) --------
// grid (kB, nch), 512 threads. r0_off: base row offset (block-3 last-chunk mode).
__global__ __launch_bounds__(512) void tail8f_k(
    const float* __restrict__ qkv_cur, const float* __restrict__ in_res,
    const float* __restrict__ Wo, const float* __restrict__ bo,
    const float* __restrict__ g0, const float* __restrict__ lb0,
    const float* __restrict__ Um, const float* __restrict__ a0m,
    const float* __restrict__ Gm, const float* __restrict__ c0m,
    const float* __restrict__ g1, const float* __restrict__ lb1,
    const float* __restrict__ W1, const float* __restrict__ fb1,
    const float* __restrict__ W2, const float* __restrict__ fb2,
    const float* __restrict__ g2, const float* __restrict__ lb2,
    const float* __restrict__ wvec, float* __restrict__ act_out,
    const float* __restrict__ Wqn, const float* __restrict__ bqn,
    float* __restrict__ qkv_next, int t, int r0_off) {
    __shared__ float bufA[ROWS][kE];       // 16KB activations
    __shared__ float bufC[ROWS][kE];       // 16KB gemm output
    __shared__ float Us[kE * kH];          // 16KB
    __shared__ float att_s[8][kS];
    __shared__ float alp[ROWS][kH][4];
    __shared__ float om_s[ROWS][kH];
    __shared__ float w_s[kS];
    __shared__ float red[8][ROWS];

    const int b = blockIdx.x;
    const int r0 = r0_off + blockIdx.y * ROWS;
    const int tid = threadIdx.x;
    const int lane = tid & 63, wid = tid >> 6;
    const int kg = tid >> 6, jt = tid & 63;
    int rr[ROWS]; bool valid[ROWS];
#pragma unroll
    for (int i = 0; i < ROWS; ++i) {
        int r = r0 + i;
        valid[i] = (r < t);
        rr[i] = valid[i] ? r : (t - 1);
    }

    // stage Q rows, U, w
    for (int p = tid; p < ROWS * kE; p += 512) {
        int i = p >> 9, d = p & 511;
        bufA[i][d] = qkv_cur[(size_t)(b * kS + rr[i]) * kQ + d];
    }
    for (int p = tid; p < kE * kH; p += 512) Us[p] = Um[p];
    if (tid < t) w_s[tid] = wvec[b * kS + tid];
    __syncthreads();

    // ---- self-attention: wave wid owns row wid ----
    {
        const int i = wid;
        for (int h = 0; h < kH; ++h) {
            float sc = -3.0e38f;
            if (lane < t) {
                const float* Kr = qkv_cur + (size_t)(b * kS + lane) * kQ + kE + h * 64;
                float a = 0.f;
#pragma unroll
                for (int d4 = 0; d4 < 16; ++d4) {
                    const float4 kv = *(const float4*)(Kr + d4 * 4);
                    const float4 qv = *(const float4*)(&bufA[i][h * 64 + d4 * 4]);
                    a = fmaf(qv.x, kv.x, a); a = fmaf(qv.y, kv.y, a);
                    a = fmaf(qv.z, kv.z, a); a = fmaf(qv.w, kv.w, a);
                }
                sc = a * 0.125f;
            }
            float m = sc;
#pragma unroll
            for (int o = 32; o > 0; o >>= 1) m = fmaxf(m, __shfl_xor(m, o));
            float e = (lane < t) ? expf(sc - m) : 0.f;
            float ss = e;
#pragma unroll
            for (int o = 32; o > 0; o >>= 1) ss += __shfl_xor(ss, o);
            if (lane < t) att_s[wid][lane] = e / ss;
            float acc = 0.f;
            const float* Vb = qkv_cur + (size_t)(b * kS) * kQ + 2 * kE + h * 64 + lane;
            for (int k = 0; k < t; ++k) acc = fmaf(att_s[wid][k], Vb[(size_t)k * kQ], acc);
            bufA[i][h * 64 + lane] = acc;  // own row; head slice dead after its score
        }
    }
    __syncthreads();

    float val[ROWS], hreg[ROWS], h2reg[ROWS];

    // ---- proj + residual + LN -> h ----
    gemm_phase8(bufA, Wo, bufC, kg, jt);
    {
        float btid = bo[tid];
#pragma unroll
        for (int i = 0; i < ROWS; ++i)
            val[i] = bufC[i][tid] + btid + in_res[(size_t)(b * kS + rr[i]) * kE + tid];
        ln8_512(val, g0, lb0, red, tid);
#pragma unroll
        for (int i = 0; i < ROWS; ++i) { hreg[i] = val[i]; bufA[i][tid] = val[i]; }
    }
    __syncthreads();

    // ---- reduced cross-attn ----
    if (tid < 256) {
        int i = tid >> 5, h = (tid >> 2) & 7, cs = tid & 3;
        float a = 0.f;
        for (int e = cs * 128; e < cs * 128 + 128; ++e) a = fmaf(bufA[i][e], Us[e * kH + h], a);
        alp[i][h][cs] = a;
    }
    __syncthreads();
    if (tid < 64) {
        int i = tid >> 3, h = tid & 7;
        float a = a0m[h] + alp[i][h][0] + alp[i][h][1] + alp[i][h][2] + alp[i][h][3];
        a *= 0.125f;
        float mm = -3.0e38f;
        for (int s = 0; s < t; ++s) mm = fmaxf(mm, a * w_s[s]);
        float se = 0.f, sw = 0.f;
        for (int s = 0; s < t; ++s) {
            float ex = expf(a * w_s[s] - mm);
            se += ex;
            sw = fmaf(ex, w_s[s], sw);
        }
        om_s[i][h] = sw / se;
    }
    __syncthreads();

    // ---- crossout + residual(h) + LN -> h2 ----
    {
        float ctid = c0m[tid];
#pragma unroll
        for (int i = 0; i < ROWS; ++i) {
            float v = ctid + hreg[i];
#pragma unroll
            for (int h = 0; h < kH; ++h) v = fmaf(om_s[i][h], Gm[h * kE + tid], v);
            val[i] = v;
        }
        ln8_512(val, g1, lb1, red, tid);
#pragma unroll
        for (int i = 0; i < ROWS; ++i) { h2reg[i] = val[i]; bufA[i][tid] = val[i]; }
    }
    __syncthreads();

    // ---- FF1 + relu ----
    gemm_phase8(bufA, W1, bufC, kg, jt);
    {
        float btid = fb1[tid];
#pragma unroll
        for (int i = 0; i < ROWS; ++i) val[i] = fmaxf(bufC[i][tid] + btid, 0.f);
#pragma unroll
        for (int i = 0; i < ROWS; ++i) bufA[i][tid] = val[i];
    }
    __syncthreads();

    // ---- FF2 + residual(h2) + LN -> act_out (+ stage act for fused QKV) ----
    gemm_phase8(bufA, W2, bufC, kg, jt);
    {
        float btid = fb2[tid];
#pragma unroll
        for (int i = 0; i < ROWS; ++i) val[i] = bufC[i][tid] + btid + h2reg[i];
        ln8_512(val, g2, lb2, red, tid);
#pragma unroll
        for (int i = 0; i < ROWS; ++i) {
            if (valid[i]) act_out[(size_t)(b * kS + r0 + i) * kE + tid] = val[i];
            bufA[i][tid] = val[i];
        }
    }
    __syncthreads();

    // ---- fused QKV projection for next decoder block (row-local; proven in R7/R8) ----
    if (Wqn != nullptr) {
#pragma unroll
        for (int slab = 0; slab < 3; ++slab) {
            gemm_phase8(bufA, Wqn + (size_t)slab * kE * kE, bufC, kg, jt);
            float bj = bqn[slab * kE + tid];
#pragma unroll
            for (int i = 0; i < ROWS; ++i)
                if (valid[i])
                    qkv_next[(size_t)(b * kS + r0 + i) * kQ + slab * kE + tid] =
                        bufC[i][tid] + bj;
            __syncthreads();
        }
    }
}

// ---------------- logits: grid (157), 64 cols/block, all 32 batch rows in LDS ----------------
__global__ __launch_bounds__(256) void logits_k(const float* __restrict__ act3,
                                                const float* __restrict__ softW,
                                                const float* __restrict__ softb,
                                                float* __restrict__ logits, int tokm1) {
    __shared__ float xs[kB][kE];  // 64KB
    int tid = threadIdx.x;
    for (int p = tid; p < kB * kE; p += 256) {
        int bb = p >> 9, k = p & 511;
        xs[bb][k] = act3[(size_t)(bb * kS + tokm1) * kE + k];
    }
    __syncthreads();
    const int tx = tid & 31, ty = tid >> 5;
    int j0 = blockIdx.x * 64 + 2 * tx;
    int j0c = (j0 + 1 < kV) ? j0 : (kV - 2);
    float acc[4][2];
#pragma unroll
    for (int r = 0; r < 4; ++r) { acc[r][0] = softb[j0c]; acc[r][1] = softb[j0c + 1]; }
#pragma unroll 4
    for (int k = 0; k < kE; ++k) {
        const float2 wv = *(const float2*)(softW + (size_t)k * kV + j0c);
#pragma unroll
        for (int r = 0; r < 4; ++r) {
            float xv = xs[4 * ty + r][k];
            acc[r][0] = fmaf(xv, wv.x, acc[r][0]);
            acc[r][1] = fmaf(xv, wv.y, acc[r][1]);
        }
    }
    if (j0 + 1 < kV) {
#pragma unroll
        for (int r = 0; r < 4; ++r) {
            logits[(size_t)(4 * ty + r) * kV + j0] = acc[r][0];
            logits[(size_t)(4 * ty + r) * kV + j0 + 1] = acc[r][1];
        }
    } else if (j0 < kV) {
#pragma unroll
        for (int r = 0; r < 4; ++r) logits[(size_t)(4 * ty + r) * kV + j0] = acc[r][0];
    }
}

// ---------------- softmax + argmax + probs + Y row + fused qkv0 row ----------------
__global__ __launch_bounds__(256) void softargmax_k(const float* __restrict__ logits,
                                                    float* __restrict__ outp,
                                                    const float* __restrict__ emb,
                                                    const float* __restrict__ pe_t,
                                                    float* __restrict__ Y,
                                                    const float* __restrict__ Wq0,
                                                    const float* __restrict__ bq0,
                                                    float* __restrict__ qkv0, int tok) {
    __shared__ float redf[4];
    __shared__ int redi[4];
    __shared__ float ys[kE];
    int b = blockIdx.x, tid = threadIdx.x;
    const float* lg = logits + (size_t)b * kV;
    float m = -3.4e38f;
    int mi = 0;
    for (int j = tid; j < kV; j += 256) {
        float v = lg[j];
        if (v > m) { m = v; mi = j; }
    }
#pragma unroll
    for (int o = 32; o > 0; o >>= 1) {
        float m2 = __shfl_xor(m, o);
        int i2 = __shfl_xor(mi, o);
        if (m2 > m || (m2 == m && i2 < mi)) { m = m2; mi = i2; }
    }
    int wid = tid >> 6;
    if ((tid & 63) == 0) { redf[wid] = m; redi[wid] = mi; }
    __syncthreads();
    m = redf[0]; mi = redi[0];
#pragma unroll
    for (int wv = 1; wv < 4; ++wv) {
        if (redf[wv] > m || (redf[wv] == m && redi[wv] < mi)) { m = redf[wv]; mi = redi[wv]; }
    }
    __syncthreads();
    float ssum = 0.f;
    for (int j = tid; j < kV; j += 256) ssum += expf(lg[j] - m);
    {
#pragma unroll
        for (int o = 32; o > 0; o >>= 1) ssum += __shfl_xor(ssum, o);
        if ((tid & 63) == 0) redf[wid] = ssum;
        __syncthreads();
        ssum = redf[0] + redf[1] + redf[2] + redf[3];
    }
    float inv = 1.f / ssum;
    float* orow = outp + (size_t)b * ((size_t)kS * kV);
    for (int j = tid; j < kV; j += 256) orow[j] = expf(lg[j] - m) * inv;
    const float* erow = emb + (size_t)mi * kE;
    float* yrow = Y + (size_t)(b * kS + tok) * kE;
    for (int j = tid; j < kE; j += 256) {
        float v = erow[j] + pe_t[j];
        yrow[j] = v;
        ys[j] = v;
    }
    __syncthreads();
    // fused qkv0 row for the new token (initY-style chain)
#pragma unroll
    for (int mq = 0; mq < 6; ++mq) {
        int j = tid + 256 * mq;
        const float* Wc = Wq0 + (size_t)(j >> 9) * (kE * kE) + (j & 511);
        float acc = bq0[j];
        for (int k = 0; k < kE; ++k) acc = fmaf(ys[k], Wc[(size_t)k * kE], acc);
        qkv0[(size_t)(b * kS + tok) * kQ + j] = acc;
    }
}

// ---------------- host ----------------
extern "C" void kernel_launch(void* const* d_in, const int* in_sizes, int n_in, void* d_out,
                              int out_size, void* d_ws, size_t ws_size, hipStream_t stream) {
    const float* noise = (const float*)d_in[0];
    const float* W_in = (const float*)d_in[1];
    const float* b_in = (const float*)d_in[2];
    const float* emb = (const float*)d_in[3];
    const float* Wsa = (const float*)d_in[4];
    const float* bsa = (const float*)d_in[5];
    const float* Wca = (const float*)d_in[6];
    const float* bca = (const float*)d_in[7];
    const float* Wff = (const float*)d_in[8];
    const float* bff = (const float*)d_in[9];
    const float* ln_g = (const float*)d_in[10];
    const float* ln_b = (const float*)d_in[11];
    const float* softW = (const float*)d_in[12];
    const float* softb = (const float*)d_in[13];
    float* out = (float*)d_out;
    (void)d_ws; (void)ws_size; (void)in_sizes; (void)n_in; (void)out_size;

    float *w_, *pe_, *Y_, *qkvb_, *actb_, *lg_, *U_, *a0_, *G_, *c0_;
    hipGetSymbolAddress((void**)&w_, HIP_SYMBOL(g_w));
    hipGetSymbolAddress((void**)&pe_, HIP_SYMBOL(g_pe));
    hipGetSymbolAddress((void**)&Y_, HIP_SYMBOL(g_Y));
    hipGetSymbolAddress((void**)&qkvb_, HIP_SYMBOL(g_qkvbuf));
    hipGetSymbolAddress((void**)&actb_, HIP_SYMBOL(g_actb));
    hipGetSymbolAddress((void**)&lg_, HIP_SYMBOL(g_logits));
    hipGetSymbolAddress((void**)&U_, HIP_SYMBOL(g_U));
    hipGetSymbolAddress((void**)&a0_, HIP_SYMBOL(g_a0));
    hipGetSymbolAddress((void**)&G_, HIP_SYMBOL(g_G));
    hipGetSymbolAddress((void**)&c0_, HIP_SYMBOL(g_c0));

    float* qb[kNB];
    float* ab[kNB];
    for (int n = 0; n < kNB; ++n) {
        qb[n] = qkvb_ + (size_t)n * (kB * kS * kQ);
        ab[n] = actb_ + (size_t)n * (kB * kS * kE);
    }

    dim3 blk(256);
    hipLaunchKernelGGL(onehot_k, dim3((kB * kV + 255) / 256), blk, 0, stream, out);
    hipLaunchKernelGGL(pe_k, dim3(kS * kE / 256), blk, 0, stream, pe_);
    hipLaunchKernelGGL(compute_w_k, dim3(1), dim3(1024), 0, stream, noise, W_in, b_in, w_);
    hipLaunchKernelGGL(initY_k, dim3(kB), blk, 0, stream, emb, pe_, Y_, Wsa, bsa, qb[0]);
    hipLaunchKernelGGL(precross_k, dim3(kNB), blk, 0, stream, Wca, bca, U_, a0_, G_, c0_);

    for (int tok = 1; tok < kS; ++tok) {
        const int t = tok;
        const int nch = (t + ROWS - 1) / ROWS;
        for (int n = 0; n < kNB; ++n) {
            const float* in_res = (n == 0) ? Y_ : ab[n - 1];
            const float* Wn = Wsa + (size_t)n * 4 * kE * kE;
            const float* bn = bsa + (size_t)n * 4 * kE;
            const float* Wf = Wff + (size_t)n * 2 * kE * kE;
            const float* bf = bff + (size_t)n * 2 * kE;
            const float* Wqn = (n < 3) ? (Wsa + (size_t)(n + 1) * 4 * kE * kE) : nullptr;
            const float* bqn = (n < 3) ? (bsa + (size_t)(n + 1) * 4 * kE) : bsa;
            float* qnext = (n < 3) ? qb[n + 1] : nullptr;
            // block 3's output is only consumed at row t-1 -> single last chunk
            const int grid_y = (n == 3) ? 1 : nch;
            const int r0_off = (n == 3) ? ((t > ROWS) ? (t - ROWS) : 0) : 0;
            hipLaunchKernelGGL(tail8f_k, dim3(kB, grid_y), dim3(512), 0, stream,
                               qb[n], in_res,
                               Wn + 3 * kE * kE, bn + 3 * kE,
                               ln_g + (size_t)(n * 3 + 0) * kE, ln_b + (size_t)(n * 3 + 0) * kE,
                               U_ + n * kE * kH, a0_ + n * kH, G_ + n * kH * kE, c0_ + n * kE,
                               ln_g + (size_t)(n * 3 + 1) * kE, ln_b + (size_t)(n * 3 + 1) * kE,
                               Wf, bf, Wf + kE * kE, bf + kE,
                               ln_g + (size_t)(n * 3 + 2) * kE, ln_b + (size_t)(n * 3 + 2) * kE,
                               w_, ab[n], Wqn, bqn, qnext, t, r0_off);
        }
        hipLaunchKernelGGL(logits_k, dim3(157), blk, 0, stream, ab[3], softW, softb, lg_,
                           tok - 1);
        hipLaunchKernelGGL(softargmax_k, dim3(kB), blk, 0, stream, lg_,
                           out + (size_t)tok * kV, emb, pe_ + (size_t)tok * kE, Y_, Wsa, bsa,
                           qb[0], tok);
    }
}

// Round 10
// 20025.069 us; speedup vs baseline: 1.6007x; 1.1349x over previous
//
#include <hip/hip_runtime.h>
#include <cmath>

constexpr int kB = 32, kS = 32, kE = 512, kH = 8, kV = 10000, kNB = 4;
constexpr int kQ = 3 * kE;  // 1536
constexpr int ROWS = 8;     // rows per tail chunk

// ---------------- device scratch ----------------
__device__ float g_w[kB * kS];
__device__ float g_pe[kS * kE];
__device__ float g_Y[kB * kS * kE];
__device__ float g_qkvbuf[kNB][kB * kS * kQ];
__device__ float g_actb[kNB][kB * kS * kE];
__device__ float g_logits[kB * kV];
__device__ float g_U[kNB * kE * kH];
__device__ float g_a0[kNB * kH];
__device__ float g_G[kNB * kH * kE];
__device__ float g_c0[kNB * kE];
__device__ float g_ck[kNB * kE];
__device__ float g_cv[kNB * kE];

// ---------------- setup kernels ----------------
__global__ void onehot_k(float* __restrict__ out) {
    int i = blockIdx.x * 256 + threadIdx.x;
    if (i >= kB * kV) return;
    int b = i / kV, v = i - b * kV;
    out[(size_t)b * kS * kV + v] = (v == 0) ? 1.f : 0.f;
}

__global__ void pe_k(float* __restrict__ pe) {
    int i = blockIdx.x * 256 + threadIdx.x;  // < kS*kE
    int s = i >> 9, e = i & 511;
    int base = e & ~1;
    float div = expf((float)base * (-logf(10000.f) / (float)kE));
    float ang = (float)s * div;
    pe[i] = (e & 1) ? cosf(ang) : sinf(ang);
}

__global__ void compute_w_k(const float* __restrict__ noise, const float* __restrict__ W_in,
                            const float* __restrict__ b_in, float* __restrict__ w) {
    __shared__ float X[kB * kS], T[kB * kS];
    int tid = threadIdx.x;  // 1024
    X[tid] = noise[tid];
    __syncthreads();
    int r = tid >> 5, c = tid & 31;
    float acc = b_in[c];
    for (int k = 0; k < 32; ++k) acc = fmaf(X[r * 32 + k], W_in[k * 32 + c], acc);
    T[tid] = acc;
    __syncthreads();
    acc = b_in[32 + c];
    for (int k = 0; k < 32; ++k) acc = fmaf(T[r * 32 + k], W_in[1024 + k * 32 + c], acc);
    w[tid] = acc;
}

__global__ __launch_bounds__(256) void initY_k(const float* __restrict__ emb,
                                               const float* __restrict__ pe,
                                               float* __restrict__ Y,
                                               const float* __restrict__ Wq0,
                                               const float* __restrict__ bq0,
                                               float* __restrict__ qkv0) {
    __shared__ float ys[kE];
    int b = blockIdx.x, tid = threadIdx.x;
    for (int j = tid; j < kE; j += 256) {
        float v = emb[j] + pe[j];
        Y[(size_t)(b * kS) * kE + j] = v;
        ys[j] = v;
    }
    __syncthreads();
#pragma unroll
    for (int m = 0; m < 6; ++m) {
        int j = tid + 256 * m;
        const float* Wc = Wq0 + (size_t)(j >> 9) * (kE * kE) + (j & 511);
        float acc = bq0[j];
        for (int k = 0; k < kE; ++k) acc = fmaf(ys[k], Wc[(size_t)k * kE], acc);
        qkv0[(size_t)(b * kS) * kQ + j] = acc;
    }
}

// ---- parallel precross: colsums (grid kNB x 4) then operators (grid kNB x 4) ----
__global__ __launch_bounds__(256) void colsum_k(const float* __restrict__ Wca,
                                                float* __restrict__ ck, float* __restrict__ cv) {
    int n = blockIdx.x, q = blockIdx.y;
    const float* Wk = Wca + (size_t)n * 4 * kE * kE + kE * kE;
    const float* Wv = Wk + kE * kE;
    __shared__ float p1[2][128], p2[2][128];
    int jj = threadIdx.x & 127, half = threadIdx.x >> 7;
    int j = q * 128 + jj;
    float s1 = 0.f, s2 = 0.f;
    for (int e = half * 256; e < half * 256 + 256; ++e) {
        s1 += Wk[(size_t)e * kE + j];
        s2 += Wv[(size_t)e * kE + j];
    }
    p1[half][jj] = s1; p2[half][jj] = s2;
    __syncthreads();
    if (half == 0) {
        ck[n * kE + j] = p1[0][jj] + p1[1][jj];
        cv[n * kE + j] = p2[0][jj] + p2[1][jj];
    }
}

__global__ __launch_bounds__(256) void precross2_k(const float* __restrict__ Wca,
                                                   const float* __restrict__ bca,
                                                   const float* __restrict__ ck,
                                                   const float* __restrict__ cv,
                                                   float* __restrict__ U, float* __restrict__ a0,
                                                   float* __restrict__ G, float* __restrict__ c0) {
    int n = blockIdx.x, s = blockIdx.y;
    const float* Wq = Wca + (size_t)n * 4 * kE * kE;
    const float* Wo = Wq + 3 * kE * kE;
    const float* bq = bca + n * 4 * kE;
    const float* bv = bq + 2 * kE;
    const float* bo = bq + 3 * kE;
    __shared__ float cks[kE], cvs[kE];
    __shared__ float cred[2][128];
    int tid = threadIdx.x;
    for (int p = tid; p < kE; p += 256) { cks[p] = ck[n * kE + p]; cvs[p] = cv[n * kE + p]; }
    __syncthreads();
    // U rows e in [s*128, s*128+128)
    for (int p = tid; p < 128 * kH; p += 256) {
        int e = s * 128 + (p >> 3), h = p & 7;
        float acc = 0.f;
        for (int d = 0; d < 64; ++d) acc = fmaf(Wq[(size_t)e * kE + h * 64 + d], cks[h * 64 + d], acc);
        U[n * kE * kH + e * kH + h] = acc;
    }
    // G[h][j] for j quarter
    for (int p = tid; p < kH * 128; p += 256) {
        int h = p >> 7, j = s * 128 + (p & 127);
        float acc = 0.f;
        for (int d = 0; d < 64; ++d) acc = fmaf(cvs[h * 64 + d], Wo[(size_t)(h * 64 + d) * kE + j], acc);
        G[n * kH * kE + h * kE + j] = acc;
    }
    // c0 quarter
    {
        int jj = tid & 127, half = tid >> 7;
        int j = s * 128 + jj;
        float acc = 0.f;
        for (int e = half * 256; e < half * 256 + 256; ++e) acc = fmaf(bv[e], Wo[(size_t)e * kE + j], acc);
        cred[half][jj] = acc;
        __syncthreads();
        if (half == 0) c0[n * kE + j] = bo[j] + cred[0][jj] + cred[1][jj];
    }
    if (s == 0 && tid < kH) {
        float acc = 0.f;
        for (int d = 0; d < 64; ++d) acc = fmaf(bq[tid * 64 + d], cks[tid * 64 + d], acc);
        a0[n * kH + tid] = acc;
    }
}

// ---------------- 512-thread (8-wave) helpers (verified math order) ----------------
__device__ __forceinline__ void rowsum8_512(float v[ROWS], float (*red)[ROWS], float out[ROWS]) {
    int lane = threadIdx.x & 63, w = threadIdx.x >> 6;
#pragma unroll
    for (int i = 0; i < ROWS; ++i) {
        float s = v[i];
#pragma unroll
        for (int o = 32; o > 0; o >>= 1) s += __shfl_xor(s, o);
        v[i] = s;
    }
    if (lane == 0) {
#pragma unroll
        for (int i = 0; i < ROWS; ++i) red[w][i] = v[i];
    }
    __syncthreads();
#pragma unroll
    for (int i = 0; i < ROWS; ++i) {
        float s = 0.f;
#pragma unroll
        for (int w2 = 0; w2 < 8; ++w2) s += red[w2][i];
        out[i] = s;
    }
    __syncthreads();
}

__device__ __forceinline__ void ln8_512(float val[ROWS], const float* __restrict__ g,
                                        const float* __restrict__ bb, float (*red)[ROWS], int j) {
    float s[ROWS], mean[ROWS], var[ROWS];
#pragma unroll
    for (int i = 0; i < ROWS; ++i) s[i] = val[i];
    rowsum8_512(s, red, mean);
#pragma unroll
    for (int i = 0; i < ROWS; ++i) {
        mean[i] *= (1.f / (float)kE);
        val[i] -= mean[i];
        s[i] = val[i] * val[i];
    }
    rowsum8_512(s, red, var);
    float gj = g[j], bj = bb[j];
#pragma unroll
    for (int i = 0; i < ROWS; ++i) {
        float rstd = rsqrtf(var[i] * (1.f / (float)kE) + 1e-5f);
        val[i] = gj * val[i] * rstd + bj;
    }
}

// GEMM phase: 8 k-groups x 64 col-threads x 8 cols; unroll 8 for deeper MLP.
__device__ __forceinline__ void gemm_phase8(const float (*in)[kE], const float* __restrict__ W,
                                            float (*out)[kE], int kg, int jt) {
    float acc[ROWS][8];
#pragma unroll
    for (int i = 0; i < ROWS; ++i)
#pragma unroll
        for (int c = 0; c < 8; ++c) acc[i][c] = 0.f;
    const int kbase = kg * 64;
    const int j8 = jt * 8;
#pragma unroll 8
    for (int kk = 0; kk < 64; kk += 4) {
        float4 av[ROWS];
#pragma unroll
        for (int i = 0; i < ROWS; ++i) av[i] = *(const float4*)(&in[i][kbase + kk]);
#pragma unroll
        for (int dk = 0; dk < 4; ++dk) {
            const float* Wr = W + (size_t)(kbase + kk + dk) * kE + j8;
            const float4 wa = *(const float4*)(Wr);
            const float4 wb = *(const float4*)(Wr + 4);
#pragma unroll
            for (int i = 0; i < ROWS; ++i) {
                const float a = (dk == 0) ? av[i].x
                              : (dk == 1) ? av[i].y
                              : (dk == 2) ? av[i].z
                                          : av[i].w;
                acc[i][0] = fmaf(a, wa.x, acc[i][0]);
                acc[i][1] = fmaf(a, wa.y, acc[i][1]);
                acc[i][2] = fmaf(a, wa.z, acc[i][2]);
                acc[i][3] = fmaf(a, wa.w, acc[i][3]);
                acc[i][4] = fmaf(a, wb.x, acc[i][4]);
                acc[i][5] = fmaf(a, wb.y, acc[i][5]);
                acc[i][6] = fmaf(a, wb.z, acc[i][6]);
                acc[i][7] = fmaf(a, wb.w, acc[i][7]);
            }
        }
    }
    if (kg == 0) {
#pragma unroll
        for (int i = 0; i < ROWS; ++i) {
            *(float4*)(&out[i][j8]) = make_float4(acc[i][0], acc[i][1], acc[i][2], acc[i][3]);
            *(float4*)(&out[i][j8 + 4]) = make_float4(acc[i][4], acc[i][5], acc[i][6], acc[i][7]);
        }
    }
    __syncthreads();
#pragma unroll
    for (int r = 1; r < 8; ++r) {
        if (kg == r) {
#pragma unroll
            for (int i = 0; i < ROWS; ++i) {
                float4 c0 = *(float4*)(&out[i][j8]);
                float4 c1 = *(float4*)(&out[i][j8 + 4]);
                c0.x += acc[i][0]; c0.y += acc[i][1]; c0.z += acc[i][2]; c0.w += acc[i][3];
                c1.x += acc[i][4]; c1.y += acc[i][5]; c1.z += acc[i][6]; c1.w += acc[i][7];
                *(float4*)(&out[i][j8]) = c0;
                *(float4*)(&out[i][j8 + 4]) = c1;
            }
        }
        __syncthreads();
    }
}

// ---------------- fused tail (R9-verified, + residual prefetch) ----------------
__global__ __launch_bounds__(512) void tail8f_k(
    const float* __restrict__ qkv_cur, const float* __restrict__ in_res,
    const float* __restrict__ Wo, const float* __restrict__ bo,
    const float* __restrict__ g0, const float* __restrict__ lb0,
    const float* __restrict__ Um, const float* __restrict__ a0m,
    const float* __restrict__ Gm, const float* __restrict__ c0m,
    const float* __restrict__ g1, const float* __restrict__ lb1,
    const float* __restrict__ W1, const float* __restrict__ fb1,
    const float* __restrict__ W2, const float* __restrict__ fb2,
    const float* __restrict__ g2, const float* __restrict__ lb2,
    const float* __restrict__ wvec, float* __restrict__ act_out,
    const float* __restrict__ Wqn, const float* __restrict__ bqn,
    float* __restrict__ qkv_next, int t, int r0_off) {
    __shared__ float bufA[ROWS][kE];
    __shared__ float bufC[ROWS][kE];
    __shared__ float Us[kE * kH];
    __shared__ float att_s[8][kS];
    __shared__ float alp[ROWS][kH][4];
    __shared__ float om_s[ROWS][kH];
    __shared__ float w_s[kS];
    __shared__ float red[8][ROWS];

    const int b = blockIdx.x;
    const int r0 = r0_off + blockIdx.y * ROWS;
    const int tid = threadIdx.x;
    const int lane = tid & 63, wid = tid >> 6;
    const int kg = tid >> 6, jt = tid & 63;
    int rr[ROWS]; bool valid[ROWS];
#pragma unroll
    for (int i = 0; i < ROWS; ++i) {
        int r = r0 + i;
        valid[i] = (r < t);
        rr[i] = valid[i] ? r : (t - 1);
    }

    for (int p = tid; p < ROWS * kE; p += 512) {
        int i = p >> 9, d = p & 511;
        bufA[i][d] = qkv_cur[(size_t)(b * kS + rr[i]) * kQ + d];
    }
    for (int p = tid; p < kE * kH; p += 512) Us[p] = Um[p];
    if (tid < t) w_s[tid] = wvec[b * kS + tid];
    __syncthreads();

    // ---- self-attention: wave wid owns row wid ----
    {
        const int i = wid;
        for (int h = 0; h < kH; ++h) {
            float sc = -3.0e38f;
            if (lane < t) {
                const float* Kr = qkv_cur + (size_t)(b * kS + lane) * kQ + kE + h * 64;
                float a = 0.f;
#pragma unroll
                for (int d4 = 0; d4 < 16; ++d4) {
                    const float4 kv = *(const float4*)(Kr + d4 * 4);
                    const float4 qv = *(const float4*)(&bufA[i][h * 64 + d4 * 4]);
                    a = fmaf(qv.x, kv.x, a); a = fmaf(qv.y, kv.y, a);
                    a = fmaf(qv.z, kv.z, a); a = fmaf(qv.w, kv.w, a);
                }
                sc = a * 0.125f;
            }
            float m = sc;
#pragma unroll
            for (int o = 32; o > 0; o >>= 1) m = fmaxf(m, __shfl_xor(m, o));
            float e = (lane < t) ? expf(sc - m) : 0.f;
            float ss = e;
#pragma unroll
            for (int o = 32; o > 0; o >>= 1) ss += __shfl_xor(ss, o);
            if (lane < t) att_s[wid][lane] = e / ss;
            float acc = 0.f;
            const float* Vb = qkv_cur + (size_t)(b * kS) * kQ + 2 * kE + h * 64 + lane;
            for (int k = 0; k < t; ++k) acc = fmaf(att_s[wid][k], Vb[(size_t)k * kQ], acc);
            bufA[i][h * 64 + lane] = acc;
        }
    }
    __syncthreads();

    float val[ROWS], hreg[ROWS], h2reg[ROWS];

    // ---- proj + residual + LN -> h (residual prefetched before the W stream) ----
    float resv[ROWS];
#pragma unroll
    for (int i = 0; i < ROWS; ++i) resv[i] = in_res[(size_t)(b * kS + rr[i]) * kE + tid];
    gemm_phase8(bufA, Wo, bufC, kg, jt);
    {
        float btid = bo[tid];
#pragma unroll
        for (int i = 0; i < ROWS; ++i) val[i] = bufC[i][tid] + btid + resv[i];
        ln8_512(val, g0, lb0, red, tid);
#pragma unroll
        for (int i = 0; i < ROWS; ++i) { hreg[i] = val[i]; bufA[i][tid] = val[i]; }
    }
    __syncthreads();

    // ---- reduced cross-attn ----
    if (tid < 256) {
        int i = tid >> 5, h = (tid >> 2) & 7, cs = tid & 3;
        float a = 0.f;
        for (int e = cs * 128; e < cs * 128 + 128; ++e) a = fmaf(bufA[i][e], Us[e * kH + h], a);
        alp[i][h][cs] = a;
    }
    __syncthreads();
    if (tid < 64) {
        int i = tid >> 3, h = tid & 7;
        float a = a0m[h] + alp[i][h][0] + alp[i][h][1] + alp[i][h][2] + alp[i][h][3];
        a *= 0.125f;
        float mm = -3.0e38f;
        for (int s = 0; s < t; ++s) mm = fmaxf(mm, a * w_s[s]);
        float se = 0.f, sw = 0.f;
        for (int s = 0; s < t; ++s) {
            float ex = expf(a * w_s[s] - mm);
            se += ex;
            sw = fmaf(ex, w_s[s], sw);
        }
        om_s[i][h] = sw / se;
    }
    __syncthreads();

    // ---- crossout + residual(h) + LN -> h2 ----
    {
        float ctid = c0m[tid];
#pragma unroll
        for (int i = 0; i < ROWS; ++i) {
            float v = ctid + hreg[i];
#pragma unroll
            for (int h = 0; h < kH; ++h) v = fmaf(om_s[i][h], Gm[h * kE + tid], v);
            val[i] = v;
        }
        ln8_512(val, g1, lb1, red, tid);
#pragma unroll
        for (int i = 0; i < ROWS; ++i) { h2reg[i] = val[i]; bufA[i][tid] = val[i]; }
    }
    __syncthreads();

    // ---- FF1 + relu ----
    gemm_phase8(bufA, W1, bufC, kg, jt);
    {
        float btid = fb1[tid];
#pragma unroll
        for (int i = 0; i < ROWS; ++i) val[i] = fmaxf(bufC[i][tid] + btid, 0.f);
#pragma unroll
        for (int i = 0; i < ROWS; ++i) bufA[i][tid] = val[i];
    }
    __syncthreads();

    // ---- FF2 + residual(h2) + LN -> act_out (+ stage act for fused QKV) ----
    gemm_phase8(bufA, W2, bufC, kg, jt);
    {
        float btid = fb2[tid];
#pragma unroll
        for (int i = 0; i < ROWS; ++i) val[i] = bufC[i][tid] + btid + h2reg[i];
        ln8_512(val, g2, lb2, red, tid);
#pragma unroll
        for (int i = 0; i < ROWS; ++i) {
            if (valid[i]) act_out[(size_t)(b * kS + r0 + i) * kE + tid] = val[i];
            bufA[i][tid] = val[i];
        }
    }
    __syncthreads();

    // ---- fused QKV projection for next decoder block ----
    if (Wqn != nullptr) {
#pragma unroll
        for (int slab = 0; slab < 3; ++slab) {
            gemm_phase8(bufA, Wqn + (size_t)slab * kE * kE, bufC, kg, jt);
            float bj = bqn[slab * kE + tid];
#pragma unroll
            for (int i = 0; i < ROWS; ++i)
                if (valid[i])
                    qkv_next[(size_t)(b * kS + r0 + i) * kQ + slab * kE + tid] =
                        bufC[i][tid] + bj;
            __syncthreads();
        }
    }
}

// ---------------- logits: grid (157), 64 cols/block, all 32 batch rows in LDS ----------------
__global__ __launch_bounds__(256) void logits_k(const float* __restrict__ act3,
                                                const float* __restrict__ softW,
                                                const float* __restrict__ softb,
                                                float* __restrict__ logits, int tokm1) {
    __shared__ float xs[kB][kE];  // 64KB
    int tid = threadIdx.x;
    for (int p = tid; p < kB * kE; p += 256) {
        int bb = p >> 9, k = p & 511;
        xs[bb][k] = act3[(size_t)(bb * kS + tokm1) * kE + k];
    }
    __syncthreads();
    const int tx = tid & 31, ty = tid >> 5;
    int j0 = blockIdx.x * 64 + 2 * tx;
    int j0c = (j0 + 1 < kV) ? j0 : (kV - 2);
    float acc[4][2];
#pragma unroll
    for (int r = 0; r < 4; ++r) { acc[r][0] = softb[j0c]; acc[r][1] = softb[j0c + 1]; }
#pragma unroll 8
    for (int k = 0; k < kE; ++k) {
        const float2 wv = *(const float2*)(softW + (size_t)k * kV + j0c);
#pragma unroll
        for (int r = 0; r < 4; ++r) {
            float xv = xs[4 * ty + r][k];
            acc[r][0] = fmaf(xv, wv.x, acc[r][0]);
            acc[r][1] = fmaf(xv, wv.y, acc[r][1]);
        }
    }
    if (j0 + 1 < kV) {
#pragma unroll
        for (int r = 0; r < 4; ++r) {
            logits[(size_t)(4 * ty + r) * kV + j0] = acc[r][0];
            logits[(size_t)(4 * ty + r) * kV + j0 + 1] = acc[r][1];
        }
    } else if (j0 < kV) {
#pragma unroll
        for (int r = 0; r < 4; ++r) logits[(size_t)(4 * ty + r) * kV + j0] = acc[r][0];
    }
}

// ---------------- softmax + argmax + probs + Y row ----------------
__global__ __launch_bounds__(256) void softargmax_k(const float* __restrict__ logits,
                                                    float* __restrict__ outp,
                                                    const float* __restrict__ emb,
                                                    const float* __restrict__ pe_t,
                                                    float* __restrict__ Y, int tok) {
    __shared__ float redf[4];
    __shared__ int redi[4];
    int b = blockIdx.x, tid = threadIdx.x;
    const float* lg = logits + (size_t)b * kV;
    float m = -3.4e38f;
    int mi = 0;
    for (int j = tid; j < kV; j += 256) {
        float v = lg[j];
        if (v > m) { m = v; mi = j; }
    }
#pragma unroll
    for (int o = 32; o > 0; o >>= 1) {
        float m2 = __shfl_xor(m, o);
        int i2 = __shfl_xor(mi, o);
        if (m2 > m || (m2 == m && i2 < mi)) { m = m2; mi = i2; }
    }
    int wid = tid >> 6;
    if ((tid & 63) == 0) { redf[wid] = m; redi[wid] = mi; }
    __syncthreads();
    m = redf[0]; mi = redi[0];
#pragma unroll
    for (int wv = 1; wv < 4; ++wv) {
        if (redf[wv] > m || (redf[wv] == m && redi[wv] < mi)) { m = redf[wv]; mi = redi[wv]; }
    }
    __syncthreads();
    float ssum = 0.f;
    for (int j = tid; j < kV; j += 256) ssum += expf(lg[j] - m);
    {
#pragma unroll
        for (int o = 32; o > 0; o >>= 1) ssum += __shfl_xor(ssum, o);
        if ((tid & 63) == 0) redf[wid] = ssum;
        __syncthreads();
        ssum = redf[0] + redf[1] + redf[2] + redf[3];
    }
    float inv = 1.f / ssum;
    float* orow = outp + (size_t)b * ((size_t)kS * kV);
    for (int j = tid; j < kV; j += 256) orow[j] = expf(lg[j] - m) * inv;
    const float* erow = emb + (size_t)mi * kE;
    float* yrow = Y + (size_t)(b * kS + tok) * kE;
    for (int j = tid; j < kE; j += 256) yrow[j] = erow[j] + pe_t[j];
}

// ---------------- qkv0 row for new token, batch-shared: grid (24) (R5-verified) ----------------
__global__ __launch_bounds__(256) void qkvrow_k(const float* __restrict__ Y,
                                                const float* __restrict__ Wq0,
                                                const float* __restrict__ bq0,
                                                float* __restrict__ qkv0, int tok) {
    __shared__ float ys[kB][kE];  // 64KB
    int tid = threadIdx.x;
    for (int p = tid; p < kB * kE; p += 256) {
        int bb = p >> 9, k = p & 511;
        ys[bb][k] = Y[(size_t)(bb * kS + tok) * kE + k];
    }
    __syncthreads();
    const int tx = tid & 63, ty = tid >> 6;  // ty 0..3 -> batches 8ty..8ty+7
    const int j = blockIdx.x * 64 + tx;
    const float* Wc = Wq0 + (size_t)(j >> 9) * (kE * kE) + (j & 511);
    float acc[8];
    float bj = bq0[j];
#pragma unroll
    for (int i = 0; i < 8; ++i) acc[i] = bj;
#pragma unroll 4
    for (int k = 0; k < kE; k += 4) {
        float w0 = Wc[(size_t)(k + 0) * kE];
        float w1 = Wc[(size_t)(k + 1) * kE];
        float w2 = Wc[(size_t)(k + 2) * kE];
        float w3 = Wc[(size_t)(k + 3) * kE];
#pragma unroll
        for (int i = 0; i < 8; ++i) {
            const float4 yv = *(const float4*)(&ys[ty * 8 + i][k]);
            float a = acc[i];
            a = fmaf(yv.x, w0, a);
            a = fmaf(yv.y, w1, a);
            a = fmaf(yv.z, w2, a);
            a = fmaf(yv.w, w3, a);
            acc[i] = a;
        }
    }
#pragma unroll
    for (int i = 0; i < 8; ++i)
        qkv0[(size_t)((ty * 8 + i) * kS + tok) * kQ + j] = acc[i];
}

// ---------------- host ----------------
extern "C" void kernel_launch(void* const* d_in, const int* in_sizes, int n_in, void* d_out,
                              int out_size, void* d_ws, size_t ws_size, hipStream_t stream) {
    const float* noise = (const float*)d_in[0];
    const float* W_in = (const float*)d_in[1];
    const float* b_in = (const float*)d_in[2];
    const float* emb = (const float*)d_in[3];
    const float* Wsa = (const float*)d_in[4];
    const float* bsa = (const float*)d_in[5];
    const float* Wca = (const float*)d_in[6];
    const float* bca = (const float*)d_in[7];
    const float* Wff = (const float*)d_in[8];
    const float* bff = (const float*)d_in[9];
    const float* ln_g = (const float*)d_in[10];
    const float* ln_b = (const float*)d_in[11];
    const float* softW = (const float*)d_in[12];
    const float* softb = (const float*)d_in[13];
    float* out = (float*)d_out;
    (void)d_ws; (void)ws_size; (void)in_sizes; (void)n_in; (void)out_size;

    float *w_, *pe_, *Y_, *qkvb_, *actb_, *lg_, *U_, *a0_, *G_, *c0_, *ck_, *cv_;
    hipGetSymbolAddress((void**)&w_, HIP_SYMBOL(g_w));
    hipGetSymbolAddress((void**)&pe_, HIP_SYMBOL(g_pe));
    hipGetSymbolAddress((void**)&Y_, HIP_SYMBOL(g_Y));
    hipGetSymbolAddress((void**)&qkvb_, HIP_SYMBOL(g_qkvbuf));
    hipGetSymbolAddress((void**)&actb_, HIP_SYMBOL(g_actb));
    hipGetSymbolAddress((void**)&lg_, HIP_SYMBOL(g_logits));
    hipGetSymbolAddress((void**)&U_, HIP_SYMBOL(g_U));
    hipGetSymbolAddress((void**)&a0_, HIP_SYMBOL(g_a0));
    hipGetSymbolAddress((void**)&G_, HIP_SYMBOL(g_G));
    hipGetSymbolAddress((void**)&c0_, HIP_SYMBOL(g_c0));
    hipGetSymbolAddress((void**)&ck_, HIP_SYMBOL(g_ck));
    hipGetSymbolAddress((void**)&cv_, HIP_SYMBOL(g_cv));

    float* qb[kNB];
    float* ab[kNB];
    for (int n = 0; n < kNB; ++n) {
        qb[n] = qkvb_ + (size_t)n * (kB * kS * kQ);
        ab[n] = actb_ + (size_t)n * (kB * kS * kE);
    }

    dim3 blk(256);
    hipLaunchKernelGGL(onehot_k, dim3((kB * kV + 255) / 256), blk, 0, stream, out);
    hipLaunchKernelGGL(pe_k, dim3(kS * kE / 256), blk, 0, stream, pe_);
    hipLaunchKernelGGL(compute_w_k, dim3(1), dim3(1024), 0, stream, noise, W_in, b_in, w_);
    hipLaunchKernelGGL(initY_k, dim3(kB), blk, 0, stream, emb, pe_, Y_, Wsa, bsa, qb[0]);
    hipLaunchKernelGGL(colsum_k, dim3(kNB, 4), blk, 0, stream, Wca, ck_, cv_);
    hipLaunchKernelGGL(precross2_k, dim3(kNB, 4), blk, 0, stream, Wca, bca, ck_, cv_, U_, a0_,
                       G_, c0_);

    for (int tok = 1; tok < kS; ++tok) {
        const int t = tok;
        const int nch = (t + ROWS - 1) / ROWS;
        for (int n = 0; n < kNB; ++n) {
            const float* in_res = (n == 0) ? Y_ : ab[n - 1];
            const float* Wn = Wsa + (size_t)n * 4 * kE * kE;
            const float* bn = bsa + (size_t)n * 4 * kE;
            const float* Wf = Wff + (size_t)n * 2 * kE * kE;
            const float* bf = bff + (size_t)n * 2 * kE;
            const float* Wqn = (n < 3) ? (Wsa + (size_t)(n + 1) * 4 * kE * kE) : nullptr;
            const float* bqn = (n < 3) ? (bsa + (size_t)(n + 1) * 4 * kE) : bsa;
            float* qnext = (n < 3) ? qb[n + 1] : nullptr;
            const int grid_y = (n == 3) ? 1 : nch;
            const int r0_off = (n == 3) ? ((t > ROWS) ? (t - ROWS) : 0) : 0;
            hipLaunchKernelGGL(tail8f_k, dim3(kB, grid_y), dim3(512), 0, stream,
                               qb[n], in_res,
                               Wn + 3 * kE * kE, bn + 3 * kE,
                               ln_g + (size_t)(n * 3 + 0) * kE, ln_b + (size_t)(n * 3 + 0) * kE,
                               U_ + n * kE * kH, a0_ + n * kH, G_ + n * kH * kE, c0_ + n * kE,
                               ln_g + (size_t)(n * 3 + 1) * kE, ln_b + (size_t)(n * 3 + 1) * kE,
                               Wf, bf, Wf + kE * kE, bf + kE,
                               ln_g + (size_t)(n * 3 + 2) * kE, ln_b + (size_t)(n * 3 + 2) * kE,
                               w_, ab[n], Wqn, bqn, qnext, t, r0_off);
        }
        hipLaunchKernelGGL(logits_k, dim3(157), blk, 0, stream, ab[3], softW, softb, lg_,
                           tok - 1);
        hipLaunchKernelGGL(softargmax_k, dim3(kB), blk, 0, stream, lg_,
                           out + (size_t)tok * kV, emb, pe_ + (size_t)tok * kE, Y_, tok);
        hipLaunchKernelGGL(qkvrow_k, dim3(24), blk, 0, stream, Y_, Wsa, bsa, qb[0], tok);
    }
}